// Round 2
// baseline (3219.596 us; speedup 1.0000x reference)
//
#include <hip/hip_runtime.h>
#include <hip/hip_bf16.h>

typedef _Float16 f16;
typedef __attribute__((ext_vector_type(8))) _Float16 f16x8;
typedef __attribute__((ext_vector_type(4))) float f32x4;

#define TT 128

__device__ __forceinline__ float sigmoidf_(float x) { return 1.0f / (1.0f + __expf(-x)); }

// ---------------------------------------------------------------------------
// fp32 -> fp16 convert (n multiple of 4)
__global__ __launch_bounds__(256) void k_f2h(const float* __restrict__ in,
                                             f16* __restrict__ out, long n4) {
  long i = (long)blockIdx.x * 256 + threadIdx.x;
  if (i >= n4) return;
  float4 v = ((const float4*)in)[i];
  out[i*4+0] = (f16)v.x; out[i*4+1] = (f16)v.y;
  out[i*4+2] = (f16)v.z; out[i*4+3] = (f16)v.w;
}

// fp32 (rows,1024) -> fp16 hi|lo (rows,2048): [0,1024)=hi, [1024,2048)=lo
__global__ __launch_bounds__(256) void k_split2(const float* __restrict__ in,
                                                f16* __restrict__ out, long n4) {
  long i = (long)blockIdx.x * 256 + threadIdx.x;
  if (i >= n4) return;
  float4 v = ((const float4*)in)[i];
  long e = i * 4;
  long row = e >> 10; int col = (int)(e & 1023);
  f16* p = out + row * 2048 + col;
  f16 h0 = (f16)v.x, h1 = (f16)v.y, h2 = (f16)v.z, h3 = (f16)v.w;
  p[0] = h0; p[1] = h1; p[2] = h2; p[3] = h3;
  p[1024+0] = (f16)(v.x - (float)h0);
  p[1024+1] = (f16)(v.y - (float)h1);
  p[1024+2] = (f16)(v.z - (float)h2);
  p[1024+3] = (f16)(v.w - (float)h3);
}

// gather rule_emb rows for init_prod -> fp16 (32 x 1024)
__global__ __launch_bounds__(256) void k_gather_prod(const float* __restrict__ rule_emb,
                                                     const int* __restrict__ init_prod,
                                                     f16* __restrict__ out) {
  int i = blockIdx.x * 256 + threadIdx.x;
  int b = i >> 10, k = i & 1023;
  out[i] = (f16)rule_emb[(long)init_prod[b] * 1024 + k];
}

// h0 -> fp16 into st_hi slot 0 (st_hi layout: [b][129][1024])
__global__ __launch_bounds__(256) void k_h0(const float* __restrict__ h0,
                                            f16* __restrict__ st) {
  int i = blockIdx.x * 256 + threadIdx.x;
  int b = i >> 10, k = i & 1023;
  st[(long)b * 129 * 1024 + k] = (f16)h0[i];
}

// (B, L=512, H=1024) fp32 -> (B, H, L) fp16 transpose
__global__ __launch_bounds__(256) void k_transpose(const float* __restrict__ in,
                                                   f16* __restrict__ out) {
  __shared__ float tile[32][33];
  const int b  = blockIdx.z;
  const int l0 = blockIdx.x * 32, h0 = blockIdx.y * 32;
  in  += (long)b * 512 * 1024;
  out += (long)b * 1024 * 512;
  const int c = threadIdx.x & 31, r = threadIdx.x >> 5;
#pragma unroll
  for (int p = 0; p < 4; ++p)
    tile[r + p*8][c] = in[(long)(l0 + r + p*8) * 1024 + h0 + c];
  __syncthreads();
#pragma unroll
  for (int p = 0; p < 4; ++p)
    out[(long)(h0 + r + p*8) * 512 + l0 + c] = (f16)tile[c][r + p*8];
}

// ---------------------------------------------------------------------------
// Generic fp16 MFMA GEMM: C[M,N] = act( A[M,K] @ B[N,K]^T + addend + bias1 + bias2 )
// 128x128 tile, BK=32, 4 waves x (4x4) 16x16x32 frags.
// split3: virtual K=3072 over physical hi|lo rows (ld 2048):
//   A blocks [hi, lo, hi], B blocks [hi, hi, lo] -> Ahi*Bhi + Alo*Bhi + Ahi*Blo.
__global__ __launch_bounds__(256) void k_gemm(
    const f16* __restrict__ A, long lda, long sA,
    const f16* __restrict__ B, long ldb, long sB,
    float* outF, f16* outH, long ldc, long sC,
    f16* out2, long ld2, long s2,
    const float* addend, long ldadd, long sAdd,
    const float* __restrict__ bias1, const float* __restrict__ bias2,
    int M, int N, int K, int act, int split3)
{
  __shared__ __align__(16) f16 As[128][40];
  __shared__ __align__(16) f16 Bs[128][40];
  const int tid = threadIdx.x;
  const int w = tid >> 6, lane = tid & 63;
  const int wm = (w & 1) * 64, wn = (w >> 1) * 64;
  const int lr = lane >> 4, lc = lane & 15;
  const long m0 = (long)blockIdx.x * 128;
  const long n0 = (long)blockIdx.y * 128;
  const int z = blockIdx.z;
  A += (long)z * sA;
  B += (long)z * sB;

  f32x4 acc[4][4];
#pragma unroll
  for (int i = 0; i < 4; ++i)
#pragma unroll
    for (int j = 0; j < 4; ++j) { f32x4 zz = {0.f,0.f,0.f,0.f}; acc[i][j] = zz; }

  for (int k0 = 0; k0 < K; k0 += 32) {
    long ka = k0, kb = k0;
    if (split3) {
      int blk = k0 >> 10, kin = k0 & 1023;
      ka = kin + ((blk == 1) ? 1024 : 0);
      kb = kin + ((blk == 2) ? 1024 : 0);
    }
#pragma unroll
    for (int p = 0; p < 2; ++p) {
      int idx = p * 256 + tid;
      int row = idx >> 2, seg = idx & 3;
      uint4 va = {0, 0, 0, 0};
      if (m0 + row < M) va = *(const uint4*)(A + (m0 + row) * lda + ka + seg * 8);
      *(uint4*)&As[row][seg * 8] = va;
      uint4 vb = {0, 0, 0, 0};
      if (n0 + row < N) vb = *(const uint4*)(B + (n0 + row) * ldb + kb + seg * 8);
      *(uint4*)&Bs[row][seg * 8] = vb;
    }
    __syncthreads();
    f16x8 af[4], bfr[4];
#pragma unroll
    for (int i = 0; i < 4; ++i) af[i]  = *(const f16x8*)&As[wm + i*16 + lc][lr * 8];
#pragma unroll
    for (int j = 0; j < 4; ++j) bfr[j] = *(const f16x8*)&Bs[wn + j*16 + lc][lr * 8];
#pragma unroll
    for (int i = 0; i < 4; ++i)
#pragma unroll
      for (int j = 0; j < 4; ++j)
        acc[i][j] = __builtin_amdgcn_mfma_f32_16x16x32_f16(af[i], bfr[j], acc[i][j], 0, 0, 0);
    __syncthreads();
  }

  if (outF)   outF   += (long)z * sC;
  if (outH)   outH   += (long)z * sC;
  if (out2)   out2   += (long)z * s2;
  if (addend) addend += (long)z * sAdd;
#pragma unroll
  for (int i = 0; i < 4; ++i)
#pragma unroll
    for (int j = 0; j < 4; ++j)
#pragma unroll
      for (int r = 0; r < 4; ++r) {
        long row = m0 + wm + i * 16 + lr * 4 + r;
        long col = n0 + wn + j * 16 + lc;
        if (row < M && col < N) {
          float v = acc[i][j][r];
          if (addend) v += addend[row * ldadd + col];
          if (bias1)  v += bias1[col];
          if (bias2)  v += bias2[col];
          if (act)    v = tanhf(v);
          if (outF) outF[row * ldc + col] = v;
          if (outH) outH[row * ldc + col] = (f16)v;
          if (out2) {
            f16 hi = (f16)v;
            out2[row * ld2 + col]        = hi;
            out2[row * ld2 + 1024 + col] = (f16)(v - (float)hi);
          }
        }
      }
}

// ---------------------------------------------------------------------------
// One LSTM step. 64 blocks; block owns 16 h-indices x all 4 gates x all 32 batches.
__global__ __launch_bounds__(256) void k_lstm_step(
    const f16* __restrict__ Whh,          // (4096,1024)
    const float* __restrict__ nt_table,   // (200,4096)
    const float* __restrict__ prod_gates, // (32,4096) incl. b_ih+b_hh
    const int* __restrict__ nt_ids,       // (128,32)
    f16* __restrict__ st,                 // (32,129,1024)
    f16* __restrict__ q2,                 // (32,128,2048) hi|lo
    float* __restrict__ cbuf,             // (32,1024) fp32 carry
    int t)
{
  __shared__ __align__(16) f16 hs[32][1032];
  __shared__ float partial[2][4][64][4];
  const int tid = threadIdx.x;
  const int w = tid >> 6, lane = tid & 63;
  const int lr = lane >> 4, lc = lane & 15;
  const int j0 = blockIdx.x * 16;

  for (int i = tid; i < 32 * 128; i += 256) {
    int b = i >> 7, c8 = i & 127;
    *(uint4*)&hs[b][c8 * 8] = *(const uint4*)&st[((long)b * 129 + t) * 1024 + c8 * 8];
  }
  __syncthreads();

  const int bt = w & 1, kh = w >> 1;
  f32x4 acc[4];
#pragma unroll
  for (int g = 0; g < 4; ++g) { f32x4 zz = {0.f,0.f,0.f,0.f}; acc[g] = zz; }

  for (int kt = 0; kt < 16; ++kt) {
    int k = kh * 512 + kt * 32 + lr * 8;
    f16x8 a = *(const f16x8*)&hs[bt * 16 + lc][k];
#pragma unroll
    for (int g = 0; g < 4; ++g) {
      f16x8 bv = *(const f16x8*)(Whh + (long)(g * 1024 + j0 + lc) * 1024 + k);
      acc[g] = __builtin_amdgcn_mfma_f32_16x16x32_f16(a, bv, acc[g], 0, 0, 0);
    }
  }

  if (w >= 2) {
#pragma unroll
    for (int g = 0; g < 4; ++g)
#pragma unroll
      for (int r = 0; r < 4; ++r) partial[bt][g][lane][r] = acc[g][r];
  }
  __syncthreads();
  if (w < 2) {
#pragma unroll
    for (int g = 0; g < 4; ++g)
#pragma unroll
      for (int r = 0; r < 4; ++r) acc[g][r] += partial[bt][g][lane][r];
    const int j = j0 + lc;
#pragma unroll
    for (int r = 0; r < 4; ++r) {
      int b = bt * 16 + lr * 4 + r;
      int nid = nt_ids[t * 32 + b];
      const float* ntr = nt_table + (long)nid * 4096 + j;
      const float* pgr = prod_gates + (long)b * 4096 + j;
      float xi = acc[0][r] + ntr[0]    + pgr[0];
      float xf = acc[1][r] + ntr[1024] + pgr[1024];
      float xg = acc[2][r] + ntr[2048] + pgr[2048];
      float xo = acc[3][r] + ntr[3072] + pgr[3072];
      float ii = sigmoidf_(xi), ff = sigmoidf_(xf);
      float gg = tanhf(xg),     oo = sigmoidf_(xo);
      float cn = ff * cbuf[(long)b * 1024 + j] + ii * gg;
      cbuf[(long)b * 1024 + j] = cn;
      float hn = oo * tanhf(cn);
      f16 hi = (f16)hn;
      st[((long)b * 129 + t + 1) * 1024 + j] = hi;
      long qr = ((long)b * 128 + t) * 2048 + j;
      q2[qr]        = hi;
      q2[qr + 1024] = (f16)(hn - (float)hi);
    }
  }
}

// ---------------------------------------------------------------------------
// Row softmax over 512 cols, fp32 in -> fp16 out. One block per row.
__global__ __launch_bounds__(256) void k_softmax(const float* __restrict__ in,
                                                 f16* __restrict__ out) {
  long row = blockIdx.x;
  in  += row * 512;
  out += row * 512;
  const int tid = threadIdx.x, w = tid >> 6, lane = tid & 63;
  float2 v = ((const float2*)in)[tid];
  float m = fmaxf(v.x, v.y);
#pragma unroll
  for (int off = 32; off; off >>= 1) m = fmaxf(m, __shfl_xor(m, off));
  __shared__ float red[8];
  if (lane == 0) red[w] = m;
  __syncthreads();
  m = fmaxf(fmaxf(red[0], red[1]), fmaxf(red[2], red[3]));
  float e0 = __expf(v.x - m), e1 = __expf(v.y - m);
  float s = e0 + e1;
#pragma unroll
  for (int off = 32; off; off >>= 1) s += __shfl_xor(s, off);
  if (lane == 0) red[4 + w] = s;
  __syncthreads();
  s = red[4] + red[5] + red[6] + red[7];
  float inv = 1.0f / s;
  out[tid * 2]     = (f16)(e0 * inv);
  out[tid * 2 + 1] = (f16)(e1 * inv);
}

// ---------------------------------------------------------------------------
extern "C" void kernel_launch(void* const* d_in, const int* in_sizes, int n_in,
                              void* d_out, int out_size, void* d_ws, size_t ws_size,
                              hipStream_t stream)
{
  const int*   init_prod = (const int*)d_in[0];
  const int*   nt_ids    = (const int*)d_in[1];
  const float* h0   = (const float*)d_in[2];
  const float* c0   = (const float*)d_in[3];
  const float* nl   = (const float*)d_in[4];
  const float* env  = (const float*)d_in[5];
  const float* nt_emb   = (const float*)d_in[6];
  const float* rule_emb = (const float*)d_in[7];
  const float* W_ih = (const float*)d_in[8];
  const float* W_hh = (const float*)d_in[9];
  const float* b_ih = (const float*)d_in[10];
  const float* b_hh = (const float*)d_in[11];
  const float* Wz   = (const float*)d_in[12];
  const float* bz   = (const float*)d_in[13];
  const float* We   = (const float*)d_in[14];
  const float* be   = (const float*)d_in[15];
  const float* Wc   = (const float*)d_in[16];
  const float* bc   = (const float*)d_in[17];
  float* out = (float*)d_out;
  (void)in_sizes; (void)n_in; (void)out_size; (void)ws_size;

  size_t off = 0;
  auto carve = [&](size_t bytes) {
    char* p = (char*)d_ws + off;
    off += (bytes + 255) & ~(size_t)255;
    return (void*)p;
  };
  f16*   Whh_h   = (f16*)carve(4096L * 1024 * 2);
  f16*   Wz_h    = (f16*)carve(1024L * 2048 * 2);
  f16*   We_h    = (f16*)carve(1024L * 2048 * 2);
  f16*   Wc_h    = (f16*)carve(1024L * 3072 * 2);
  f16*   nte_h   = (f16*)carve(200L * 1024 * 2);
  f16*   prod_h  = (f16*)carve(32L * 1024 * 2);
  float* nt_table   = (float*)carve(200L * 4096 * 4);
  float* prod_gates = (float*)carve(32L * 4096 * 4);
  f16*   st_hi   = (f16*)carve(32L * 129 * 1024 * 2);
  float* cbuf    = (float*)carve(32L * 1024 * 4);
  f16*   q2      = (f16*)carve(32L * 128 * 2048 * 2);  // h hi|lo; later zt hi|lo
  f16*   ctxT    = (f16*)carve(32L * 1024 * 512 * 2);  // nlT then envT
  f16*   ctx2    = (f16*)carve(32L * 512 * 2048 * 2);  // Wih_h at start; then nl/env hi|lo
  float* scores  = (float*)carve(32L * 128 * 512 * 4);
  f16*   attn    = (f16*)carve(32L * 128 * 512 * 2);
  f16*   mix     = (f16*)carve(32L * 128 * 1024 * 2);
  f16*   et      = (f16*)carve(32L * 128 * 1024 * 2);
  float* tmp     = (float*)carve(32L * 128 * 1024 * 4);
  f16*   Wih_h   = (f16*)ctx2;  // alias: Wih dead before ctx2 first written

  auto f2h = [&](const float* src, f16* dst, long n) {
    long n4 = n / 4;
    k_f2h<<<dim3((unsigned)((n4 + 255) / 256)), dim3(256), 0, stream>>>(src, dst, n4);
  };
  f2h(W_ih, Wih_h, 4096L * 2048);
  f2h(W_hh, Whh_h, 4096L * 1024);
  f2h(Wz,   Wz_h,  1024L * 2048);
  f2h(We,   We_h,  1024L * 2048);
  f2h(Wc,   Wc_h,  1024L * 3072);
  f2h(nt_emb, nte_h, 200L * 1024);
  k_gather_prod<<<dim3(128), dim3(256), 0, stream>>>(rule_emb, init_prod, prod_h);
  k_h0<<<dim3(128), dim3(256), 0, stream>>>(h0, st_hi);
  hipMemcpyAsync(cbuf, c0, 32L * 1024 * 4, hipMemcpyDeviceToDevice, stream);

  auto gemm = [&](const f16* A, long lda, long sA,
                  const f16* B, long ldb, long sB,
                  float* oF, f16* oH, long ldc, long sC,
                  f16* o2, long ld2, long s2,
                  const float* add, long ldadd, long sAdd,
                  const float* bias1, const float* bias2,
                  int M, int N, int K, int act, int split3, int batch) {
    dim3 grid((unsigned)((M + 127) / 128), (unsigned)((N + 127) / 128), (unsigned)batch);
    k_gemm<<<grid, dim3(256), 0, stream>>>(A, lda, sA, B, ldb, sB,
                                           oF, oH, ldc, sC, o2, ld2, s2,
                                           add, ldadd, sAdd, bias1, bias2,
                                           M, N, K, act, split3);
  };

  // gate tables
  gemm(nte_h, 1024, 0, Wih_h, 2048, 0, nt_table, nullptr, 4096, 0,
       nullptr, 0, 0, nullptr, 0, 0, nullptr, nullptr, 200, 4096, 1024, 0, 0, 1);
  gemm(prod_h, 1024, 0, Wih_h + 1024, 2048, 0, prod_gates, nullptr, 4096, 0,
       nullptr, 0, 0, nullptr, 0, 0, b_ih, b_hh, 32, 4096, 1024, 0, 0, 1);

  // serial LSTM recurrence; h_t (hi|lo) into q2, hi into st_hi slots 1..128
  for (int t = 0; t < TT; ++t)
    k_lstm_step<<<dim3(64), dim3(256), 0, stream>>>(Whh_h, nt_table, prod_gates,
                                                    nt_ids, st_hi, q2, cbuf, t);

  // --- attention over nl ---
  k_split2<<<dim3(16384), dim3(256), 0, stream>>>(nl, ctx2, 32L * 512 * 1024 / 4);
  k_transpose<<<dim3(16, 32, 32), dim3(256), 0, stream>>>(nl, ctxT);
  gemm(q2, 2048, 128L * 2048, ctx2, 2048, 512L * 2048, scores, nullptr, 512, 128L * 512,
       nullptr, 0, 0, nullptr, 0, 0, nullptr, nullptr, 128, 512, 3072, 0, 1, 32);
  k_softmax<<<dim3(32 * 128), dim3(256), 0, stream>>>(scores, attn);
  gemm(attn, 512, 128L * 512, ctxT, 512, 1024L * 512, nullptr, mix, 1024, 128L * 1024,
       nullptr, 0, 0, nullptr, 0, 0, nullptr, nullptr, 128, 1024, 512, 0, 0, 32);
  // zt = tanh(mix @ WzA^T + st @ WzB^T + bz) -> hi|lo into q2 (reuse)
  gemm(mix, 1024, 0, Wz_h, 2048, 0, tmp, nullptr, 1024, 0,
       nullptr, 0, 0, nullptr, 0, 0, nullptr, nullptr, 4096, 1024, 1024, 0, 0, 1);
  gemm(st_hi + 1024, 1024, 129L * 1024, Wz_h + 1024, 2048, 0, nullptr, nullptr, 0, 0,
       q2, 2048, 128L * 2048, tmp, 1024, 128L * 1024, bz, nullptr,
       128, 1024, 1024, 1, 0, 32);

  // --- attention over env ---
  k_split2<<<dim3(16384), dim3(256), 0, stream>>>(env, ctx2, 32L * 512 * 1024 / 4);
  k_transpose<<<dim3(16, 32, 32), dim3(256), 0, stream>>>(env, ctxT);
  gemm(q2, 2048, 128L * 2048, ctx2, 2048, 512L * 2048, scores, nullptr, 512, 128L * 512,
       nullptr, 0, 0, nullptr, 0, 0, nullptr, nullptr, 128, 512, 3072, 0, 1, 32);
  k_softmax<<<dim3(32 * 128), dim3(256), 0, stream>>>(scores, attn);
  gemm(attn, 512, 128L * 512, ctxT, 512, 1024L * 512, nullptr, mix, 1024, 128L * 1024,
       nullptr, 0, 0, nullptr, 0, 0, nullptr, nullptr, 128, 1024, 512, 0, 0, 32);
  // et = tanh(mix @ WeA^T + zt @ WeB^T + be)
  gemm(mix, 1024, 0, We_h, 2048, 0, tmp, nullptr, 1024, 0,
       nullptr, 0, 0, nullptr, 0, 0, nullptr, nullptr, 4096, 1024, 1024, 0, 0, 1);
  gemm(q2, 2048, 0, We_h + 1024, 2048, 0, nullptr, et, 1024, 0,
       nullptr, 0, 0, tmp, 1024, 0, be, nullptr, 4096, 1024, 1024, 1, 0, 1);

  // --- ct = tanh(st@WcS^T + zt@WcZ^T + et@WcE^T + bc) -> d_out (T,B,H) ---
  gemm(q2, 2048, 0, Wc_h + 1024, 3072, 0, tmp, nullptr, 1024, 0,
       nullptr, 0, 0, nullptr, 0, 0, nullptr, nullptr, 4096, 1024, 1024, 0, 0, 1);
  gemm(et, 1024, 0, Wc_h + 2048, 3072, 0, tmp, nullptr, 1024, 0,
       nullptr, 0, 0, tmp, 1024, 0, nullptr, nullptr, 4096, 1024, 1024, 0, 0, 1);
  gemm(st_hi + 1024, 1024, 129L * 1024, Wc_h, 3072, 0, out, nullptr, 32L * 1024, 1024,
       nullptr, 0, 0, tmp, 1024, 128L * 1024, bc, nullptr, 128, 1024, 1024, 1, 0, 32);
}

// Round 3
// 2744.679 us; speedup vs baseline: 1.1730x; 1.1730x over previous
//
#include <hip/hip_runtime.h>
#include <hip/hip_bf16.h>

typedef _Float16 f16;
typedef __attribute__((ext_vector_type(8))) _Float16 f16x8;
typedef __attribute__((ext_vector_type(4))) float f32x4;

#define TT 128

__device__ __forceinline__ float sigmoidf_(float x) { return 1.0f / (1.0f + __expf(-x)); }

// ---------------------------------------------------------------------------
// fp32 -> fp16 convert (n multiple of 4)
__global__ __launch_bounds__(256) void k_f2h(const float* __restrict__ in,
                                             f16* __restrict__ out, long n4) {
  long i = (long)blockIdx.x * 256 + threadIdx.x;
  if (i >= n4) return;
  float4 v = ((const float4*)in)[i];
  out[i*4+0] = (f16)v.x; out[i*4+1] = (f16)v.y;
  out[i*4+2] = (f16)v.z; out[i*4+3] = (f16)v.w;
}

// gather rule_emb rows for init_prod -> fp16 (32 x 1024)
__global__ __launch_bounds__(256) void k_gather_prod(const float* __restrict__ rule_emb,
                                                     const int* __restrict__ init_prod,
                                                     f16* __restrict__ out) {
  int i = blockIdx.x * 256 + threadIdx.x;
  int b = i >> 10, k = i & 1023;
  out[i] = (f16)rule_emb[(long)init_prod[b] * 1024 + k];
}

// h0 -> fp16 into st_hi slot 0 (st_hi layout: [b][129][1024])
__global__ __launch_bounds__(256) void k_h0(const float* __restrict__ h0,
                                            f16* __restrict__ st) {
  int i = blockIdx.x * 256 + threadIdx.x;
  int b = i >> 10, k = i & 1023;
  st[(long)b * 129 * 1024 + k] = (f16)h0[i];
}

// (B, L=512, H=1024) fp32 -> outT (B, H, L) f16  AND  outN (B, L, H) f16
__global__ __launch_bounds__(256) void k_transpose(const float* __restrict__ in,
                                                   f16* __restrict__ outT,
                                                   f16* __restrict__ outN) {
  __shared__ float tile[32][33];
  const int b  = blockIdx.z;
  const int l0 = blockIdx.x * 32, h0 = blockIdx.y * 32;
  in   += (long)b * 512 * 1024;
  outT += (long)b * 1024 * 512;
  outN += (long)b * 512 * 1024;
  const int c = threadIdx.x & 31, r = threadIdx.x >> 5;
#pragma unroll
  for (int p = 0; p < 4; ++p) {
    float v = in[(long)(l0 + r + p*8) * 1024 + h0 + c];
    tile[r + p*8][c] = v;
    outN[(long)(l0 + r + p*8) * 1024 + h0 + c] = (f16)v;
  }
  __syncthreads();
#pragma unroll
  for (int p = 0; p < 4; ++p)
    outT[(long)(h0 + r + p*8) * 512 + l0 + c] = (f16)tile[c][r + p*8];
}

// ---------------------------------------------------------------------------
// fp16 MFMA GEMM: C[M,N] = act( A[M,K] @ B[N,K]^T + bias1 + bias2 )
// 128x128 tile, BK=32, register-prefetch double buffer.
// bmod: B K-index wraps mod bmod (for [q_hi|q_lo] x [ctx|ctx] split GEMM).
// zdiv: split-K; z -> (batch = z/zdiv, slice = z%zdiv), slice covers K/zdiv,
//       fp32 partial written at outF + batch*sF + slice*sSl.
// Outputs (any subset): outF fp32, outH f16, outH2 f16, out2 f16 hi|lo pairs.
__global__ __launch_bounds__(256) void k_gemm(
    const f16* __restrict__ A, long lda, long sA,
    const f16* __restrict__ B, long ldb, long sB,
    float* __restrict__ outF, long ldF, long sF, long sSl,
    f16* __restrict__ outH, long ldH, long sH,
    f16* __restrict__ outH2, long ldH2, long sH2,
    f16* __restrict__ out2, long ld2, long s2,
    const float* __restrict__ bias1, const float* __restrict__ bias2,
    int M, int N, int K, int act, int bmod, int zdiv)
{
  __shared__ __align__(16) f16 As[128][40];
  __shared__ __align__(16) f16 Bs[128][40];
  const int tid = threadIdx.x;
  const int w = tid >> 6, lane = tid & 63;
  const int wm = (w & 1) * 64, wn = (w >> 1) * 64;
  const int lr = lane >> 4, lc = lane & 15;
  const long m0 = (long)blockIdx.x * 128;
  const long n0 = (long)blockIdx.y * 128;
  int z = blockIdx.z, batch = z, slice = 0, Ks = K;
  if (zdiv > 1) { batch = z / zdiv; slice = z - batch * zdiv; Ks = K / zdiv; }
  const long kbeg = (long)slice * Ks;
  A += (long)batch * sA;
  B += (long)batch * sB;

  const int rr = tid >> 2, sg = (tid & 3) * 8;   // staging row (0..63 +p*64), K seg
  const int nIt = Ks / 32;

  uint4 pa[2], pb[2];
  {
    long k = kbeg;
    long kb = bmod ? (k & (bmod - 1)) : k;
#pragma unroll
    for (int p = 0; p < 2; ++p) {
      int row = p * 64 + rr;
      uint4 va = {0,0,0,0}, vb = {0,0,0,0};
      if (m0 + row < M) va = *(const uint4*)(A + (m0 + row) * lda + k + sg);
      if (n0 + row < N) vb = *(const uint4*)(B + (n0 + row) * ldb + kb + sg);
      pa[p] = va; pb[p] = vb;
    }
  }

  f32x4 acc[4][4];
#pragma unroll
  for (int i = 0; i < 4; ++i)
#pragma unroll
    for (int j = 0; j < 4; ++j) { f32x4 zz = {0.f,0.f,0.f,0.f}; acc[i][j] = zz; }

  for (int it = 0; it < nIt; ++it) {
#pragma unroll
    for (int p = 0; p < 2; ++p) {
      *(uint4*)&As[p * 64 + rr][sg] = pa[p];
      *(uint4*)&Bs[p * 64 + rr][sg] = pb[p];
    }
    __syncthreads();
    if (it + 1 < nIt) {                      // prefetch next tile during MFMAs
      long k = kbeg + (long)(it + 1) * 32;
      long kb = bmod ? (k & (bmod - 1)) : k;
#pragma unroll
      for (int p = 0; p < 2; ++p) {
        int row = p * 64 + rr;
        uint4 va = {0,0,0,0}, vb = {0,0,0,0};
        if (m0 + row < M) va = *(const uint4*)(A + (m0 + row) * lda + k + sg);
        if (n0 + row < N) vb = *(const uint4*)(B + (n0 + row) * ldb + kb + sg);
        pa[p] = va; pb[p] = vb;
      }
    }
    f16x8 af[4], bf[4];
#pragma unroll
    for (int i = 0; i < 4; ++i) af[i] = *(const f16x8*)&As[wm + i*16 + lc][lr * 8];
#pragma unroll
    for (int j = 0; j < 4; ++j) bf[j] = *(const f16x8*)&Bs[wn + j*16 + lc][lr * 8];
#pragma unroll
    for (int i = 0; i < 4; ++i)
#pragma unroll
      for (int j = 0; j < 4; ++j)
        acc[i][j] = __builtin_amdgcn_mfma_f32_16x16x32_f16(af[i], bf[j], acc[i][j], 0, 0, 0);
    __syncthreads();
  }

  if (outF)  outF  += (long)batch * sF + (long)slice * sSl;
  if (outH)  outH  += (long)batch * sH;
  if (outH2) outH2 += (long)batch * sH2;
  if (out2)  out2  += (long)batch * s2;
#pragma unroll
  for (int i = 0; i < 4; ++i)
#pragma unroll
    for (int j = 0; j < 4; ++j)
#pragma unroll
      for (int r = 0; r < 4; ++r) {
        long row = m0 + wm + i * 16 + lr * 4 + r;
        long col = n0 + wn + j * 16 + lc;
        if (row < M && col < N) {
          float v = acc[i][j][r];
          if (bias1) v += bias1[col];
          if (bias2) v += bias2[col];
          if (act)   v = tanhf(v);
          if (outF)  outF[row * ldF + col] = v;
          if (outH)  outH[row * ldH + col] = (f16)v;
          if (outH2) outH2[row * ldH2 + col] = (f16)v;
          if (out2) {
            f16 hi = (f16)v;
            out2[row * ld2 + col]        = hi;
            out2[row * ld2 + 1024 + col] = (f16)(v - (float)hi);
          }
        }
      }
}

// ---------------------------------------------------------------------------
// One LSTM step. 64 blocks; block owns 16 h-indices x all 4 gates x 32 batches.
// Writes h_{t+1}: st slot t+1 (staging), q2 hi|lo (scores), X col [0,1024)
// (ct GEMM input), Y1 col [1024,2048) (zt GEMM input).
__global__ __launch_bounds__(256) void k_lstm_step(
    const f16* __restrict__ Whh,          // (4096,1024)
    const float* __restrict__ nt_table,   // (200,4096)
    const float* __restrict__ prod_gates, // (32,4096) incl. b_ih+b_hh
    const int* __restrict__ nt_ids,       // (128,32)
    f16* __restrict__ st,                 // (32,129,1024)
    f16* __restrict__ q2,                 // (4096,2048) hi|lo, row b*128+t
    f16* __restrict__ X,                  // (4096,3072), row b*128+t
    f16* __restrict__ Y1,                 // (4096,2048)
    float* __restrict__ cbuf,             // (32,1024) fp32 carry
    int t)
{
  __shared__ __align__(16) f16 hs[32][1032];
  __shared__ float partial[2][4][64][4];
  const int tid = threadIdx.x;
  const int w = tid >> 6, lane = tid & 63;
  const int lr = lane >> 4, lc = lane & 15;
  const int j0 = blockIdx.x * 16;

  for (int i = tid; i < 32 * 128; i += 256) {
    int b = i >> 7, c8 = i & 127;
    *(uint4*)&hs[b][c8 * 8] = *(const uint4*)&st[((long)b * 129 + t) * 1024 + c8 * 8];
  }
  __syncthreads();

  const int bt = w & 1, kh = w >> 1;
  f32x4 acc[4];
#pragma unroll
  for (int g = 0; g < 4; ++g) { f32x4 zz = {0.f,0.f,0.f,0.f}; acc[g] = zz; }

  for (int kt = 0; kt < 16; ++kt) {
    int k = kh * 512 + kt * 32 + lr * 8;
    f16x8 a = *(const f16x8*)&hs[bt * 16 + lc][k];
#pragma unroll
    for (int g = 0; g < 4; ++g) {
      f16x8 bv = *(const f16x8*)(Whh + (long)(g * 1024 + j0 + lc) * 1024 + k);
      acc[g] = __builtin_amdgcn_mfma_f32_16x16x32_f16(a, bv, acc[g], 0, 0, 0);
    }
  }

  if (w >= 2) {
#pragma unroll
    for (int g = 0; g < 4; ++g)
#pragma unroll
      for (int r = 0; r < 4; ++r) partial[bt][g][lane][r] = acc[g][r];
  }
  __syncthreads();
  if (w < 2) {
#pragma unroll
    for (int g = 0; g < 4; ++g)
#pragma unroll
      for (int r = 0; r < 4; ++r) acc[g][r] += partial[bt][g][lane][r];
    const int j = j0 + lc;
#pragma unroll
    for (int r = 0; r < 4; ++r) {
      int b = bt * 16 + lr * 4 + r;
      int nid = nt_ids[t * 32 + b];
      const float* ntr = nt_table + (long)nid * 4096 + j;
      const float* pgr = prod_gates + (long)b * 4096 + j;
      float xi = acc[0][r] + ntr[0]    + pgr[0];
      float xf = acc[1][r] + ntr[1024] + pgr[1024];
      float xg = acc[2][r] + ntr[2048] + pgr[2048];
      float xo = acc[3][r] + ntr[3072] + pgr[3072];
      float ii = sigmoidf_(xi), ff = sigmoidf_(xf);
      float gg = tanhf(xg),     oo = sigmoidf_(xo);
      float cn = ff * cbuf[(long)b * 1024 + j] + ii * gg;
      cbuf[(long)b * 1024 + j] = cn;
      float hn = oo * tanhf(cn);
      f16 hi = (f16)hn;
      st[((long)b * 129 + t + 1) * 1024 + j] = hi;
      long row = (long)b * 128 + t;
      q2[row * 2048 + j]        = hi;
      q2[row * 2048 + 1024 + j] = (f16)(hn - (float)hi);
      X[row * 3072 + j]         = hi;
      Y1[row * 2048 + 1024 + j] = hi;
    }
  }
}

// ---------------------------------------------------------------------------
// Row softmax over 512 cols of (p0+p1), fp32 in -> fp16 out. One block per row.
__global__ __launch_bounds__(256) void k_softmax2(const float* __restrict__ p0,
                                                  const float* __restrict__ p1,
                                                  f16* __restrict__ out) {
  long row = blockIdx.x;
  p0  += row * 512;
  p1  += row * 512;
  out += row * 512;
  const int tid = threadIdx.x, w = tid >> 6, lane = tid & 63;
  float2 a = ((const float2*)p0)[tid];
  float2 b = ((const float2*)p1)[tid];
  float vx = a.x + b.x, vy = a.y + b.y;
  float m = fmaxf(vx, vy);
#pragma unroll
  for (int off = 32; off; off >>= 1) m = fmaxf(m, __shfl_xor(m, off));
  __shared__ float red[8];
  if (lane == 0) red[w] = m;
  __syncthreads();
  m = fmaxf(fmaxf(red[0], red[1]), fmaxf(red[2], red[3]));
  float e0 = __expf(vx - m), e1 = __expf(vy - m);
  float s = e0 + e1;
#pragma unroll
  for (int off = 32; off; off >>= 1) s += __shfl_xor(s, off);
  if (lane == 0) red[4 + w] = s;
  __syncthreads();
  s = red[4] + red[5] + red[6] + red[7];
  float inv = 1.0f / s;
  out[tid * 2]     = (f16)(e0 * inv);
  out[tid * 2 + 1] = (f16)(e1 * inv);
}

// ---------------------------------------------------------------------------
extern "C" void kernel_launch(void* const* d_in, const int* in_sizes, int n_in,
                              void* d_out, int out_size, void* d_ws, size_t ws_size,
                              hipStream_t stream)
{
  const int*   init_prod = (const int*)d_in[0];
  const int*   nt_ids    = (const int*)d_in[1];
  const float* h0   = (const float*)d_in[2];
  const float* c0   = (const float*)d_in[3];
  const float* nl   = (const float*)d_in[4];
  const float* env  = (const float*)d_in[5];
  const float* nt_emb   = (const float*)d_in[6];
  const float* rule_emb = (const float*)d_in[7];
  const float* W_ih = (const float*)d_in[8];
  const float* W_hh = (const float*)d_in[9];
  const float* b_ih = (const float*)d_in[10];
  const float* b_hh = (const float*)d_in[11];
  const float* Wz   = (const float*)d_in[12];
  const float* bz   = (const float*)d_in[13];
  const float* We   = (const float*)d_in[14];
  const float* be   = (const float*)d_in[15];
  const float* Wc   = (const float*)d_in[16];
  const float* bc   = (const float*)d_in[17];
  float* out = (float*)d_out;
  (void)in_sizes; (void)n_in; (void)out_size; (void)ws_size;

  size_t off = 0;
  auto carve = [&](size_t bytes) {
    char* p = (char*)d_ws + off;
    off += (bytes + 255) & ~(size_t)255;
    return (void*)p;
  };
  f16*   Whh_h   = (f16*)carve(4096L * 1024 * 2);
  f16*   Wz_h    = (f16*)carve(1024L * 2048 * 2);
  f16*   We_h    = (f16*)carve(1024L * 2048 * 2);
  f16*   Wc_h    = (f16*)carve(1024L * 3072 * 2);
  f16*   nte_h   = (f16*)carve(200L * 1024 * 2);
  f16*   prod_h  = (f16*)carve(32L * 1024 * 2);
  float* nt_table   = (float*)carve(200L * 4096 * 4);
  float* prod_gates = (float*)carve(32L * 4096 * 4);
  f16*   st_hi   = (f16*)carve(32L * 129 * 1024 * 2);
  float* cbuf    = (float*)carve(32L * 1024 * 4);
  f16*   q2      = (f16*)carve(4096L * 2048 * 2);   // query hi|lo (h, then zt)
  f16*   X       = (f16*)carve(4096L * 3072 * 2);   // [h | zt | et] for ct GEMM
  f16*   Y1      = (f16*)carve(4096L * 2048 * 2);   // [mix1 | h]  for zt GEMM
  f16*   Y2      = (f16*)carve(4096L * 2048 * 2);   // [mix2 | zt] for et GEMM
  f16*   ctx_h   = (f16*)carve(32L * 512 * 1024 * 2);  // f16 context (nl, then env)
  f16*   ctxT    = (f16*)carve(32L * 1024 * 512 * 2);  // transposed context
  float* scoresP = (float*)carve(2L * 32 * 128 * 512 * 4);  // split-K partials
  f16*   attn    = (f16*)carve(4096L * 512 * 2);
  f16*   Wih_h   = (f16*)X;   // alias: Wih only needed before lstm writes X

  auto f2h = [&](const float* src, f16* dst, long n) {
    long n4 = n / 4;
    k_f2h<<<dim3((unsigned)((n4 + 255) / 256)), dim3(256), 0, stream>>>(src, dst, n4);
  };
  f2h(W_ih, Wih_h, 4096L * 2048);
  f2h(W_hh, Whh_h, 4096L * 1024);
  f2h(Wz,   Wz_h,  1024L * 2048);
  f2h(We,   We_h,  1024L * 2048);
  f2h(Wc,   Wc_h,  1024L * 3072);
  f2h(nt_emb, nte_h, 200L * 1024);
  k_gather_prod<<<dim3(128), dim3(256), 0, stream>>>(rule_emb, init_prod, prod_h);
  k_h0<<<dim3(128), dim3(256), 0, stream>>>(h0, st_hi);
  hipMemcpyAsync(cbuf, c0, 32L * 1024 * 4, hipMemcpyDeviceToDevice, stream);

  auto gemm = [&](const f16* A, long lda, long sA,
                  const f16* B, long ldb, long sB,
                  float* oF, long ldF, long sF, long sSl,
                  f16* oH, long ldH, long sH,
                  f16* oH2, long ldH2, long sH2,
                  f16* o2, long ld2, long s2,
                  const float* b1, const float* b2,
                  int M, int N, int K, int act, int bmod, int zdiv, int batch) {
    dim3 grid((unsigned)((M + 127) / 128), (unsigned)((N + 127) / 128),
              (unsigned)(batch * zdiv));
    k_gemm<<<grid, dim3(256), 0, stream>>>(A, lda, sA, B, ldb, sB,
                                           oF, ldF, sF, sSl, oH, ldH, sH,
                                           oH2, ldH2, sH2, o2, ld2, s2,
                                           b1, b2, M, N, K, act, bmod, zdiv);
  };
  const long SPL = 32L * 128 * 512;   // split-K slice plane (floats)

  // gate tables
  gemm(nte_h, 1024, 0, Wih_h, 2048, 0, nt_table, 4096, 0, 0,
       nullptr,0,0, nullptr,0,0, nullptr,0,0, nullptr, nullptr,
       200, 4096, 1024, 0, 0, 1, 1);
  gemm(prod_h, 1024, 0, Wih_h + 1024, 2048, 0, prod_gates, 4096, 0, 0,
       nullptr,0,0, nullptr,0,0, nullptr,0,0, b_ih, b_hh,
       32, 4096, 1024, 0, 0, 1, 1);

  // serial LSTM recurrence
  for (int t = 0; t < TT; ++t)
    k_lstm_step<<<dim3(64), dim3(256), 0, stream>>>(Whh_h, nt_table, prod_gates,
                                                    nt_ids, st_hi, q2, X, Y1, cbuf, t);

  // --- attention over nl ---
  k_transpose<<<dim3(16, 32, 32), dim3(256), 0, stream>>>(nl, ctxT, ctx_h);
  // scores = [q_hi|q_lo] @ [ctx|ctx]^T, K=2048, split-K=2 partials
  gemm(q2, 2048, 128L * 2048, ctx_h, 1024, 512L * 1024,
       scoresP, 512, 128L * 512, SPL, nullptr,0,0, nullptr,0,0, nullptr,0,0,
       nullptr, nullptr, 128, 512, 2048, 0, 1024, 2, 32);
  k_softmax2<<<dim3(4096), dim3(256), 0, stream>>>(scoresP, scoresP + SPL, attn);
  // mix1 = attn @ ctxT^T -> Y1[:,0:1024)
  gemm(attn, 512, 128L * 512, ctxT, 512, 1024L * 512,
       nullptr,0,0,0, Y1, 2048, 128L * 2048, nullptr,0,0, nullptr,0,0,
       nullptr, nullptr, 128, 1024, 512, 0, 0, 1, 32);
  // zt = tanh(Y1=[mix1|h] @ Wz^T + bz) -> X[:,1024:2048), Y2[:,1024:2048), q2 hi|lo
  gemm(Y1, 2048, 0, Wz_h, 2048, 0,
       nullptr,0,0,0, X + 1024, 3072, 0, Y2 + 1024, 2048, 0, q2, 2048, 0,
       bz, nullptr, 4096, 1024, 2048, 1, 0, 1, 1);

  // --- attention over env ---
  k_transpose<<<dim3(16, 32, 32), dim3(256), 0, stream>>>(env, ctxT, ctx_h);
  gemm(q2, 2048, 128L * 2048, ctx_h, 1024, 512L * 1024,
       scoresP, 512, 128L * 512, SPL, nullptr,0,0, nullptr,0,0, nullptr,0,0,
       nullptr, nullptr, 128, 512, 2048, 0, 1024, 2, 32);
  k_softmax2<<<dim3(4096), dim3(256), 0, stream>>>(scoresP, scoresP + SPL, attn);
  // mix2 -> Y2[:,0:1024)
  gemm(attn, 512, 128L * 512, ctxT, 512, 1024L * 512,
       nullptr,0,0,0, Y2, 2048, 128L * 2048, nullptr,0,0, nullptr,0,0,
       nullptr, nullptr, 128, 1024, 512, 0, 0, 1, 32);
  // et = tanh(Y2=[mix2|zt] @ We^T + be) -> X[:,2048:3072)
  gemm(Y2, 2048, 0, We_h, 2048, 0,
       nullptr,0,0,0, X + 2048, 3072, 0, nullptr,0,0, nullptr,0,0,
       be, nullptr, 4096, 1024, 2048, 1, 0, 1, 1);

  // --- ct = tanh(X=[h|zt|et] @ Wc^T + bc) -> d_out (T,B,H) ---
  gemm(X, 3072, 128L * 3072, Wc_h, 3072, 0,
       out, 32L * 1024, 1024, 0, nullptr,0,0, nullptr,0,0, nullptr,0,0,
       bc, nullptr, 128, 1024, 3072, 1, 0, 1, 32);
}